// Round 1
// baseline (254.267 us; speedup 1.0000x reference)
//
#include <hip/hip_runtime.h>
#include <stdint.h>

// Problem constants
#define DIMC   768
#define NHEAD  12
#define HDIM   64
#define BATCH  8
#define SEQ    1024
#define NTOK   (BATCH*SEQ)      // 8192
#define QKVN   (3*DIMC)         // 2304
#define ATT_SCALE 0.125f        // 64^-0.5

typedef unsigned short u16;
typedef __attribute__((ext_vector_type(8))) __bf16 bf16x8;
typedef __attribute__((ext_vector_type(4))) float  f32x4;

#define MFMA16(a,b,c) __builtin_amdgcn_mfma_f32_16x16x32_bf16(a,b,c,0,0,0)

__device__ __forceinline__ u16 f2bf(float f) {
  union { float f; uint32_t u; } v; v.f = f;
  uint32_t u = v.u;
  u += 0x7fffu + ((u >> 16) & 1u);   // RN-even (inputs are normal floats)
  return (u16)(u >> 16);
}

__device__ __forceinline__ void gload16(const void* g, void* l) {
  __builtin_amdgcn_global_load_lds((const __attribute__((address_space(1))) void*)g,
                                   (__attribute__((address_space(3))) void*)l,
                                   16, 0, 0);
}

// ---------------- fp32 -> bf16 convert ----------------
__global__ __launch_bounds__(256) void cvt_bf16(const float* __restrict__ src,
                                                u16* __restrict__ dst, int n) {
  int i = (blockIdx.x * 256 + threadIdx.x) * 8;
  if (i + 8 > n) return;
  float a[8];
  __builtin_memcpy(a, src + i, 32);
  u16 o[8];
#pragma unroll
  for (int k = 0; k < 8; ++k) o[k] = f2bf(a[k]);
  __builtin_memcpy(dst + i, o, 16);
}

// ---------------- NT GEMM: C[M,N] = A[M,K] * B[N,K]^T + bias ----------------
// MODE 0: write fp32 out[M,N].
// MODE 1: QKV scatter: col -> (s,h,d); Q,K as [b,h,n,d] bf16; V transposed [b,h,d,n] bf16.
template<int MODE>
__global__ __launch_bounds__(256)
void gemm_nt(const u16* __restrict__ A, const u16* __restrict__ B,
             const float* __restrict__ bias, float* __restrict__ outF,
             u16* __restrict__ Qb, u16* __restrict__ Kb, u16* __restrict__ Vt,
             int M, int N, int K) {
  __shared__ u16 sA[128 * 32];
  __shared__ u16 sB[128 * 32];
  const int tid = threadIdx.x;
  const int wave = tid >> 6, lane = tid & 63;
  const int quad = lane >> 4, l15 = lane & 15;
  const int bm = blockIdx.y * 128, bn = blockIdx.x * 128;
  const int wr = (wave >> 1) * 64, wc = (wave & 1) * 64;

  // staging: g in [0,512): row=g>>2, 16B-seg=g&3; LDS elem off = g*8
  const int g0 = tid, g1 = tid + 256;
  const u16* Ag0 = A + (size_t)(bm + (g0 >> 2)) * K + (g0 & 3) * 8;
  const u16* Ag1 = A + (size_t)(bm + (g1 >> 2)) * K + (g1 & 3) * 8;
  const u16* Bg0 = B + (size_t)(bn + (g0 >> 2)) * K + (g0 & 3) * 8;
  const u16* Bg1 = B + (size_t)(bn + (g1 >> 2)) * K + (g1 & 3) * 8;

  f32x4 acc[4][4] = {};
  const int nk = K >> 5;
  for (int kt = 0; kt < nk; ++kt) {
    __syncthreads();
    gload16(Ag0 + kt * 32, sA + g0 * 8);
    gload16(Ag1 + kt * 32, sA + g1 * 8);
    gload16(Bg0 + kt * 32, sB + g0 * 8);
    gload16(Bg1 + kt * 32, sB + g1 * 8);
    __syncthreads();
    bf16x8 af[4], bfr[4];
#pragma unroll
    for (int t = 0; t < 4; ++t) {
      __builtin_memcpy(&af[t],  &sA[(wr + t * 16 + l15) * 32 + quad * 8], 16);
      __builtin_memcpy(&bfr[t], &sB[(wc + t * 16 + l15) * 32 + quad * 8], 16);
    }
#pragma unroll
    for (int i = 0; i < 4; ++i)
#pragma unroll
      for (int j = 0; j < 4; ++j)
        acc[i][j] = MFMA16(af[i], bfr[j], acc[i][j]);
  }

  // epilogue: D[row=(lane>>4)*4+r][col=lane&15] (m89-verified)
#pragma unroll
  for (int i = 0; i < 4; ++i) {
    const int row0 = bm + wr + i * 16 + quad * 4;
#pragma unroll
    for (int j = 0; j < 4; ++j) {
      const int col = bn + wc + j * 16 + l15;
      const float bv = bias[col];
      if (MODE == 0) {
#pragma unroll
        for (int r = 0; r < 4; ++r)
          outF[(size_t)(row0 + r) * N + col] = acc[i][j][r] + bv;
      } else {
        const int s = col / DIMC;
        const int rem = col - s * DIMC;
        const int h = rem >> 6, d = rem & 63;
        const int b = row0 >> 10, n0 = row0 & 1023;
        const int bh = b * NHEAD + h;
        if (s == 2) {            // V transposed: [bh][d][n], 4 regs = 4 consecutive n
          u16 pk[4];
#pragma unroll
          for (int r = 0; r < 4; ++r) pk[r] = f2bf(acc[i][j][r] + bv);
          __builtin_memcpy(Vt + (((size_t)bh * 64 + d) << 10) + n0, pk, 8);
        } else {                 // Q/K: [bh][n][d]
          u16* dst = (s == 0 ? Qb : Kb) + (((size_t)bh << 10) + n0) * 64 + d;
#pragma unroll
          for (int r = 0; r < 4; ++r) dst[r * 64] = f2bf(acc[i][j][r] + bv);
        }
      }
    }
  }
}

// ---------------- flash attention ----------------
// grid = B*H*16 blocks; block handles 64 Q rows; wave w owns rows [w*16, w*16+16).
#define LPAD 72   // LDS row stride (elements): 144B, 16B-aligned, bank-stride 36 -> <=2-way
__global__ __launch_bounds__(256)
void attn_fwd(const u16* __restrict__ Qb, const u16* __restrict__ Kb,
              const u16* __restrict__ Vt, u16* __restrict__ AO) {
  __shared__ u16 sQ[64 * LPAD];
  __shared__ u16 sK[64 * LPAD];
  __shared__ u16 sV[64 * LPAD];   // [d][key]
  __shared__ u16 sP[64 * LPAD];   // [row][key], wave-private strips
  const int tid = threadIdx.x;
  const int wave = tid >> 6, lane = tid & 63;
  const int quad = lane >> 4, l15 = lane & 15;
  const int bid = blockIdx.x;
  const int qb = bid & 15, bh = bid >> 4;
  const int b = bh / NHEAD, h = bh - b * NHEAD;
  const u16* Qp = Qb + ((size_t)bh << 16);
  const u16* Kp = Kb + ((size_t)bh << 16);
  const u16* Vp = Vt + ((size_t)bh << 16);

  // load Q block (64x64): g in [0,512): row=g>>3, seg=g&7
#pragma unroll
  for (int i = 0; i < 2; ++i) {
    const int g = i * 256 + tid, row = g >> 3, seg = g & 7;
    uint4 v;
    __builtin_memcpy(&v, Qp + ((qb << 6) + row) * 64 + seg * 8, 16);
    __builtin_memcpy(&sQ[row * LPAD + seg * 8], &v, 16);
  }

  float mrow[4], lrow[4];
  f32x4 o_acc[4] = {};
#pragma unroll
  for (int r = 0; r < 4; ++r) { mrow[r] = -INFINITY; lrow[r] = 0.f; }

  for (int kc = 0; kc < 16; ++kc) {
    __syncthreads();
#pragma unroll
    for (int i = 0; i < 2; ++i) {
      const int g = i * 256 + tid, row = g >> 3, seg = g & 7;
      uint4 vk, vv;
      __builtin_memcpy(&vk, Kp + ((kc << 6) + row) * 64 + seg * 8, 16);
      __builtin_memcpy(&vv, Vp + (row << 10) + (kc << 6) + seg * 8, 16);
      __builtin_memcpy(&sK[row * LPAD + seg * 8], &vk, 16);
      __builtin_memcpy(&sV[row * LPAD + seg * 8], &vv, 16);
    }
    __syncthreads();

    // S strip [16 x 64] = Q_strip * Kc^T
    f32x4 s_acc[4] = {};
#pragma unroll
    for (int ks = 0; ks < 2; ++ks) {
      bf16x8 aq;
      __builtin_memcpy(&aq, &sQ[((wave << 4) + l15) * LPAD + ks * 32 + quad * 8], 16);
#pragma unroll
      for (int tc = 0; tc < 4; ++tc) {
        bf16x8 bk;
        __builtin_memcpy(&bk, &sK[(tc * 16 + l15) * LPAD + ks * 32 + quad * 8], 16);
        s_acc[tc] = MFMA16(aq, bk, s_acc[tc]);
      }
    }

    // online softmax per row (row = quad*4 + r; cols spread over l15 and tc)
    float al[4];
#pragma unroll
    for (int r = 0; r < 4; ++r) {
#pragma unroll
      for (int tc = 0; tc < 4; ++tc) s_acc[tc][r] *= ATT_SCALE;
      float mx = fmaxf(fmaxf(s_acc[0][r], s_acc[1][r]), fmaxf(s_acc[2][r], s_acc[3][r]));
      mx = fmaxf(mx, __shfl_xor(mx, 1));
      mx = fmaxf(mx, __shfl_xor(mx, 2));
      mx = fmaxf(mx, __shfl_xor(mx, 4));
      mx = fmaxf(mx, __shfl_xor(mx, 8));
      const float mnew = fmaxf(mrow[r], mx);
      al[r] = __expf(mrow[r] - mnew);
      mrow[r] = mnew;
      float sum = 0.f;
#pragma unroll
      for (int tc = 0; tc < 4; ++tc) {
        const float p = __expf(s_acc[tc][r] - mnew);
        s_acc[tc][r] = p;
        sum += p;
      }
      sum += __shfl_xor(sum, 1);
      sum += __shfl_xor(sum, 2);
      sum += __shfl_xor(sum, 4);
      sum += __shfl_xor(sum, 8);
      lrow[r] = lrow[r] * al[r] + sum;
    }

    // P (C-layout) -> LDS (A-layout round trip, m120 pattern); wave-private strip
#pragma unroll
    for (int r = 0; r < 4; ++r)
#pragma unroll
      for (int tc = 0; tc < 4; ++tc)
        sP[((wave << 4) + quad * 4 + r) * LPAD + tc * 16 + l15] = f2bf(s_acc[tc][r]);

    // rescale O, then O += P * Vc
#pragma unroll
    for (int tc = 0; tc < 4; ++tc)
#pragma unroll
      for (int r = 0; r < 4; ++r) o_acc[tc][r] *= al[r];

    __builtin_amdgcn_s_waitcnt(0);  // drain sP writes before same-wave ds_read
#pragma unroll
    for (int ks = 0; ks < 2; ++ks) {
      bf16x8 pa;
      __builtin_memcpy(&pa, &sP[((wave << 4) + l15) * LPAD + ks * 32 + quad * 8], 16);
#pragma unroll
      for (int tc = 0; tc < 4; ++tc) {
        bf16x8 vb;
        __builtin_memcpy(&vb, &sV[(tc * 16 + l15) * LPAD + ks * 32 + quad * 8], 16);
        o_acc[tc] = MFMA16(pa, vb, o_acc[tc]);
      }
    }
  }

  // epilogue: AO[b][n][h*64+d] bf16
  float inv[4];
#pragma unroll
  for (int r = 0; r < 4; ++r) inv[r] = 1.0f / lrow[r];
  const int nbase = (qb << 6) + (wave << 4) + quad * 4;
#pragma unroll
  for (int tc = 0; tc < 4; ++tc) {
    const int col = h * 64 + tc * 16 + l15;
#pragma unroll
    for (int r = 0; r < 4; ++r)
      AO[(size_t)((b << 10) + nbase + r) * DIMC + col] = f2bf(o_acc[tc][r] * inv[r]);
  }
}

// ---------------- launch ----------------
extern "C" void kernel_launch(void* const* d_in, const int* in_sizes, int n_in,
                              void* d_out, int out_size, void* d_ws, size_t ws_size,
                              hipStream_t stream) {
  const float* x      = (const float*)d_in[0];   // [8,1024,768]
  const float* w_qkv  = (const float*)d_in[1];   // [2304,768]
  const float* b_qkv  = (const float*)d_in[2];   // [2304]
  const float* w_proj = (const float*)d_in[3];   // [768,768]
  const float* b_proj = (const float*)d_in[4];   // [768]
  float* out = (float*)d_out;

  const int nX = NTOK * DIMC;          // 6291456
  const int nWq = QKVN * DIMC;         // 1769472
  const int nWp = DIMC * DIMC;         // 589824
  u16* Xb    = (u16*)d_ws;
  u16* Wqkvb = Xb + nX;
  u16* Wprojb = Wqkvb + nWq;
  u16* Qb    = Wprojb + nWp;
  u16* Kb    = Qb + nX;
  u16* Vt    = Kb + nX;
  u16* AO    = Vt + nX;

  cvt_bf16<<<nX / 2048,  256, 0, stream>>>(x,      Xb,     nX);
  cvt_bf16<<<nWq / 2048, 256, 0, stream>>>(w_qkv,  Wqkvb,  nWq);
  cvt_bf16<<<nWp / 2048, 256, 0, stream>>>(w_proj, Wprojb, nWp);

  dim3 g1(QKVN / 128, NTOK / 128);
  gemm_nt<1><<<g1, 256, 0, stream>>>(Xb, Wqkvb, b_qkv, nullptr, Qb, Kb, Vt,
                                     NTOK, QKVN, DIMC);

  attn_fwd<<<BATCH * NHEAD * (SEQ / 64), 256, 0, stream>>>(Qb, Kb, Vt, AO);

  dim3 g2(DIMC / 128, NTOK / 128);
  gemm_nt<0><<<g2, 256, 0, stream>>>(AO, Wprojb, b_proj, out, nullptr, nullptr, nullptr,
                                     NTOK, DIMC, DIMC);
}

// Round 2
// 241.009 us; speedup vs baseline: 1.0550x; 1.0550x over previous
//
#include <hip/hip_runtime.h>
#include <stdint.h>

// Problem constants
#define DIMC   768
#define NHEAD  12
#define HDIM   64
#define BATCH  8
#define SEQ    1024
#define NTOK   (BATCH*SEQ)      // 8192
#define QKVN   (3*DIMC)         // 2304
// Q is pre-scaled by 0.125 * log2(e) so softmax is exp2(S) directly.
#define QSCALE 0.18033688011112042f

typedef unsigned short u16;
typedef __attribute__((ext_vector_type(8))) __bf16 bf16x8;
typedef __attribute__((ext_vector_type(2))) __bf16 bf16x2;
typedef __attribute__((ext_vector_type(4))) float  f32x4;

#define MFMA16(a,b,c) __builtin_amdgcn_mfma_f32_16x16x32_bf16(a,b,c,0,0,0)

__device__ __forceinline__ u16 f2bf(float f) {
  union { float f; uint32_t u; } v; v.f = f;
  uint32_t u = v.u;
  u += 0x7fffu + ((u >> 16) & 1u);   // RN-even (inputs are normal floats)
  return (u16)(u >> 16);
}

__device__ __forceinline__ uint32_t pack2(float a, float b) {
  bf16x2 t = { (__bf16)a, (__bf16)b };
  uint32_t r; __builtin_memcpy(&r, &t, 4); return r;
}

__device__ __forceinline__ void gload16(const void* g, void* l) {
  __builtin_amdgcn_global_load_lds((const __attribute__((address_space(1))) void*)g,
                                   (__attribute__((address_space(3))) void*)l,
                                   16, 0, 0);
}

// ---------------- fp32 -> bf16 convert ----------------
__global__ __launch_bounds__(256) void cvt_bf16(const float* __restrict__ src,
                                                u16* __restrict__ dst, int n) {
  int i = (blockIdx.x * 256 + threadIdx.x) * 8;
  if (i + 8 > n) return;
  float a[8];
  __builtin_memcpy(a, src + i, 32);
  u16 o[8];
#pragma unroll
  for (int k = 0; k < 8; ++k) o[k] = f2bf(a[k]);
  __builtin_memcpy(dst + i, o, 16);
}

// ---------------- NT GEMM: C[M,N] = A[M,K] * B[N,K]^T + bias ----------------
// MODE 0: write fp32 out[M,N].
// MODE 1: QKV scatter: col -> (s,h,d); Q (pre-scaled), K as [b,h,n,d] bf16; V transposed [b,h,d,n] bf16.
template<int MODE>
__global__ __launch_bounds__(256)
void gemm_nt(const u16* __restrict__ A, const u16* __restrict__ B,
             const float* __restrict__ bias, float* __restrict__ outF,
             u16* __restrict__ Qb, u16* __restrict__ Kb, u16* __restrict__ Vt,
             int M, int N, int K) {
  __shared__ u16 sA[128 * 32];
  __shared__ u16 sB[128 * 32];
  const int tid = threadIdx.x;
  const int wave = tid >> 6, lane = tid & 63;
  const int quad = lane >> 4, l15 = lane & 15;
  const int bm = blockIdx.y * 128, bn = blockIdx.x * 128;
  const int wr = (wave >> 1) * 64, wc = (wave & 1) * 64;

  const int g0 = tid, g1 = tid + 256;
  const u16* Ag0 = A + (size_t)(bm + (g0 >> 2)) * K + (g0 & 3) * 8;
  const u16* Ag1 = A + (size_t)(bm + (g1 >> 2)) * K + (g1 & 3) * 8;
  const u16* Bg0 = B + (size_t)(bn + (g0 >> 2)) * K + (g0 & 3) * 8;
  const u16* Bg1 = B + (size_t)(bn + (g1 >> 2)) * K + (g1 & 3) * 8;

  f32x4 acc[4][4] = {};
  const int nk = K >> 5;
  for (int kt = 0; kt < nk; ++kt) {
    __syncthreads();
    gload16(Ag0 + kt * 32, sA + g0 * 8);
    gload16(Ag1 + kt * 32, sA + g1 * 8);
    gload16(Bg0 + kt * 32, sB + g0 * 8);
    gload16(Bg1 + kt * 32, sB + g1 * 8);
    __syncthreads();
    bf16x8 af[4], bfr[4];
#pragma unroll
    for (int t = 0; t < 4; ++t) {
      __builtin_memcpy(&af[t],  &sA[(wr + t * 16 + l15) * 32 + quad * 8], 16);
      __builtin_memcpy(&bfr[t], &sB[(wc + t * 16 + l15) * 32 + quad * 8], 16);
    }
#pragma unroll
    for (int i = 0; i < 4; ++i)
#pragma unroll
      for (int j = 0; j < 4; ++j)
        acc[i][j] = MFMA16(af[i], bfr[j], acc[i][j]);
  }

  // epilogue: D[row=(lane>>4)*4+r][col=lane&15]
#pragma unroll
  for (int i = 0; i < 4; ++i) {
    const int row0 = bm + wr + i * 16 + quad * 4;
#pragma unroll
    for (int j = 0; j < 4; ++j) {
      const int col = bn + wc + j * 16 + l15;
      const float bv = bias[col];
      if (MODE == 0) {
#pragma unroll
        for (int r = 0; r < 4; ++r)
          outF[(size_t)(row0 + r) * N + col] = acc[i][j][r] + bv;
      } else {
        const int s = col / DIMC;
        const int rem = col - s * DIMC;
        const int h = rem >> 6, d = rem & 63;
        const int b = row0 >> 10, n0 = row0 & 1023;
        const int bh = b * NHEAD + h;
        if (s == 2) {            // V transposed: [bh][d][n]
          u16 pk[4];
#pragma unroll
          for (int r = 0; r < 4; ++r) pk[r] = f2bf(acc[i][j][r] + bv);
          __builtin_memcpy(Vt + (((size_t)bh * 64 + d) << 10) + n0, pk, 8);
        } else {                 // Q/K: [bh][n][d]; Q pre-scaled by QSCALE
          const float sc = (s == 0) ? QSCALE : 1.0f;
          u16* dst = (s == 0 ? Qb : Kb) + (((size_t)bh << 10) + n0) * 64 + d;
#pragma unroll
          for (int r = 0; r < 4; ++r) dst[r * 64] = f2bf((acc[i][j][r] + bv) * sc);
        }
      }
    }
  }
}

// ---------------- flash attention (no-max streaming softmax, S^T orientation) ----
// grid = B*H*8 blocks; block = 128 Q rows, 4 waves x 32 rows; 64-key chunks.
#define LP 72   // LDS row stride in u16 elems: 144B (16B-aligned)
__global__ __launch_bounds__(256, 3)
void attn_fwd(const u16* __restrict__ Qb, const u16* __restrict__ Kb,
              const u16* __restrict__ Vt, u16* __restrict__ AO) {
  __shared__ __align__(16) u16 sK[64 * LP];        // [key][d]
  __shared__ __align__(16) u16 sV[64 * LP];        // [d][key]
  __shared__ __align__(16) u16 sP[4][32 * LP];     // per-wave [q][key]
  const int tid = threadIdx.x;
  const int wave = tid >> 6, lane = tid & 63;
  const int quad = lane >> 4, l15 = lane & 15;
  const int bid = blockIdx.x;
  const int qb = bid & 7, bh = bid >> 3;
  const int b = bh / NHEAD, h = bh - b * NHEAD;
  const u16* Qp = Qb + ((size_t)bh << 16);
  const u16* Kp = Kb + ((size_t)bh << 16);
  const u16* Vp = Vt + ((size_t)bh << 16);
  u16* sPw = sP[wave];
  const int qrow0 = qb * 128 + wave * 32;

  // Q fragments in registers (B-operand: lane l15 = q, quad*8+j = d), pre-scaled.
  bf16x8 qf[2][2];
#pragma unroll
  for (int qt = 0; qt < 2; ++qt)
#pragma unroll
    for (int ks = 0; ks < 2; ++ks)
      __builtin_memcpy(&qf[qt][ks],
                       Qp + (qrow0 + qt * 16 + l15) * 64 + ks * 32 + quad * 8, 16);

  f32x4 oacc[4][2] = {};   // O^T accum: [dtile][qtile], row=d, col=q
  float Lsum[2] = {0.f, 0.f};

  for (int kc = 0; kc < 16; ++kc) {
    __syncthreads();
    // stage K chunk (contiguous 8KB) and V chunk (64 rows of 128B)
#pragma unroll
    for (int i = 0; i < 2; ++i) {
      const int g = i * 256 + tid, row = g >> 3, seg = g & 7;
      uint4 vk = *(const uint4*)(Kp + (kc << 12) + g * 8);
      uint4 vv = *(const uint4*)(Vp + (row << 10) + (kc << 6) + seg * 8);
      *(uint4*)&sK[row * LP + seg * 8] = vk;
      *(uint4*)&sV[row * LP + seg * 8] = vv;
    }
    __syncthreads();

    // S^T[key 64][q 32] = K * Q^T  (A=K: m=key, B=Q: n=q)
    f32x4 st[4][2] = {};
#pragma unroll
    for (int ks = 0; ks < 2; ++ks) {
      bf16x8 kf[4];
#pragma unroll
      for (int kt = 0; kt < 4; ++kt)
        kf[kt] = *(const bf16x8*)&sK[(kt * 16 + l15) * LP + ks * 32 + quad * 8];
#pragma unroll
      for (int kt = 0; kt < 4; ++kt)
#pragma unroll
        for (int qt = 0; qt < 2; ++qt)
          st[kt][qt] = MFMA16(kf[kt], qf[qt][ks], st[kt][qt]);
    }

    // p = exp2(S) (Q carries 0.125*log2e); accumulate L; pack to sP[q][key]
#pragma unroll
    for (int kt = 0; kt < 4; ++kt)
#pragma unroll
      for (int qt = 0; qt < 2; ++qt) {
        float p0 = __builtin_amdgcn_exp2f(st[kt][qt][0]);
        float p1 = __builtin_amdgcn_exp2f(st[kt][qt][1]);
        float p2 = __builtin_amdgcn_exp2f(st[kt][qt][2]);
        float p3 = __builtin_amdgcn_exp2f(st[kt][qt][3]);
        Lsum[qt] += (p0 + p1) + (p2 + p3);
        uint2 w = { pack2(p0, p1), pack2(p2, p3) };
        *(uint2*)&sPw[(qt * 16 + l15) * LP + kt * 16 + quad * 4] = w;
      }

    __builtin_amdgcn_s_waitcnt(0);  // drain sP writes before same-wave reads

    // O^T[d 64][q 32] += V^T * P^T  (A=V^T from sV[d][key], B=P^T from sP[q][key])
#pragma unroll
    for (int ks = 0; ks < 2; ++ks) {
      bf16x8 vf[4], pf[2];
#pragma unroll
      for (int dt = 0; dt < 4; ++dt)
        vf[dt] = *(const bf16x8*)&sV[(dt * 16 + l15) * LP + ks * 32 + quad * 8];
#pragma unroll
      for (int qt = 0; qt < 2; ++qt)
        pf[qt] = *(const bf16x8*)&sPw[(qt * 16 + l15) * LP + ks * 32 + quad * 8];
#pragma unroll
      for (int dt = 0; dt < 4; ++dt)
#pragma unroll
        for (int qt = 0; qt < 2; ++qt)
          oacc[dt][qt] = MFMA16(vf[dt], pf[qt], oacc[dt][qt]);
    }
  }

  // final: cross-quad L reduction (lanes quad vary in bits 4,5), normalize, store
  float inv[2];
#pragma unroll
  for (int qt = 0; qt < 2; ++qt) {
    float l = Lsum[qt];
    l += __shfl_xor(l, 16);
    l += __shfl_xor(l, 32);
    inv[qt] = 1.0f / l;
  }
  // O^T C-layout: row=d=dt*16+quad*4+r, col=q=l15. Pack 4 d's -> 8B store.
#pragma unroll
  for (int dt = 0; dt < 4; ++dt)
#pragma unroll
    for (int qt = 0; qt < 2; ++qt) {
      const int n = qrow0 + qt * 16 + l15;
      uint2 w = { pack2(oacc[dt][qt][0] * inv[qt], oacc[dt][qt][1] * inv[qt]),
                  pack2(oacc[dt][qt][2] * inv[qt], oacc[dt][qt][3] * inv[qt]) };
      *(uint2*)(AO + (size_t)((b << 10) + n) * DIMC + h * 64 + dt * 16 + quad * 4) = w;
    }
}

// ---------------- launch ----------------
extern "C" void kernel_launch(void* const* d_in, const int* in_sizes, int n_in,
                              void* d_out, int out_size, void* d_ws, size_t ws_size,
                              hipStream_t stream) {
  const float* x      = (const float*)d_in[0];   // [8,1024,768]
  const float* w_qkv  = (const float*)d_in[1];   // [2304,768]
  const float* b_qkv  = (const float*)d_in[2];   // [2304]
  const float* w_proj = (const float*)d_in[3];   // [768,768]
  const float* b_proj = (const float*)d_in[4];   // [768]
  float* out = (float*)d_out;

  const int nX = NTOK * DIMC;          // 6291456
  const int nWq = QKVN * DIMC;         // 1769472
  const int nWp = DIMC * DIMC;         // 589824
  u16* Xb    = (u16*)d_ws;
  u16* Wqkvb = Xb + nX;
  u16* Wprojb = Wqkvb + nWq;
  u16* Qb    = Wprojb + nWp;
  u16* Kb    = Qb + nX;
  u16* Vt    = Kb + nX;
  u16* AO    = Vt + nX;

  cvt_bf16<<<nX / 2048,  256, 0, stream>>>(x,      Xb,     nX);
  cvt_bf16<<<nWq / 2048, 256, 0, stream>>>(w_qkv,  Wqkvb,  nWq);
  cvt_bf16<<<nWp / 2048, 256, 0, stream>>>(w_proj, Wprojb, nWp);

  dim3 g1(QKVN / 128, NTOK / 128);
  gemm_nt<1><<<g1, 256, 0, stream>>>(Xb, Wqkvb, b_qkv, nullptr, Qb, Kb, Vt,
                                     NTOK, QKVN, DIMC);

  attn_fwd<<<BATCH * NHEAD * (SEQ / 64), 256, 0, stream>>>(Qb, Kb, Vt, AO);

  dim3 g2(DIMC / 128, NTOK / 128);
  gemm_nt<0><<<g2, 256, 0, stream>>>(AO, Wprojb, b_proj, out, nullptr, nullptr, nullptr,
                                     NTOK, DIMC, DIMC);
}

// Round 3
// 197.066 us; speedup vs baseline: 1.2903x; 1.2230x over previous
//
#include <hip/hip_runtime.h>
#include <stdint.h>

// Problem constants
#define DIMC   768
#define NHEAD  12
#define HDIM   64
#define BATCH  8
#define SEQ    1024
#define NTOK   (BATCH*SEQ)      // 8192
#define QKVN   (3*DIMC)         // 2304
// Q is pre-scaled by 0.125 * log2(e) so softmax is exp2(S) directly.
#define QSCALE 0.18033688011112042f

typedef unsigned short u16;
typedef __attribute__((ext_vector_type(8))) __bf16 bf16x8;
typedef __attribute__((ext_vector_type(2))) __bf16 bf16x2;
typedef __attribute__((ext_vector_type(4))) float  f32x4;

#define MFMA16(a,b,c) __builtin_amdgcn_mfma_f32_16x16x32_bf16(a,b,c,0,0,0)

__device__ __forceinline__ u16 f2bf(float f) {
  union { float f; uint32_t u; } v; v.f = f;
  uint32_t u = v.u;
  u += 0x7fffu + ((u >> 16) & 1u);   // RN-even (inputs are normal floats)
  return (u16)(u >> 16);
}

__device__ __forceinline__ uint32_t pack2(float a, float b) {
  bf16x2 t = { (__bf16)a, (__bf16)b };
  uint32_t r; __builtin_memcpy(&r, &t, 4); return r;
}

__device__ __forceinline__ void gload16(const void* g, void* l) {
  __builtin_amdgcn_global_load_lds((const __attribute__((address_space(1))) void*)g,
                                   (__attribute__((address_space(3))) void*)l,
                                   16, 0, 0);
}

// ---------------- fused fp32 -> bf16 convert (x, w_qkv, w_proj in one launch) ----
#define NX  (NTOK*DIMC)      // 6291456
#define NWQ (QKVN*DIMC)      // 1769472
#define NWP (DIMC*DIMC)      // 589824
__global__ __launch_bounds__(256)
void cvt_all(const float* __restrict__ x, const float* __restrict__ wq,
             const float* __restrict__ wp, u16* __restrict__ dst) {
  int i = (blockIdx.x * 256 + threadIdx.x) * 8;   // dst elem index (ranges contiguous)
  const float* src;
  int off;
  if (i < NX)            { src = x;  off = i; }
  else if (i < NX + NWQ) { src = wq; off = i - NX; }
  else                   { src = wp; off = i - NX - NWQ; }
  float a[8];
  __builtin_memcpy(a, src + off, 32);
  u16 o[8];
#pragma unroll
  for (int k = 0; k < 8; ++k) o[k] = f2bf(a[k]);
  __builtin_memcpy(dst + i, o, 16);
}

// ---------------- NT GEMM: C[M,N] = A[M,K] * B[N,K]^T + bias ----------------
// MODE 0: write fp32 out[M,N].
// MODE 1: QKV scatter: Q (pre-scaled), K as [b,h,n,d] bf16; V transposed [b,h,d,n] bf16.
template<int MODE>
__global__ __launch_bounds__(256)
void gemm_nt(const u16* __restrict__ A, const u16* __restrict__ B,
             const float* __restrict__ bias, float* __restrict__ outF,
             u16* __restrict__ Qb, u16* __restrict__ Kb, u16* __restrict__ Vt,
             int M, int N, int K) {
  __shared__ u16 sA[128 * 32];
  __shared__ u16 sB[128 * 32];
  const int tid = threadIdx.x;
  const int wave = tid >> 6, lane = tid & 63;
  const int quad = lane >> 4, l15 = lane & 15;
  const int bm = blockIdx.y * 128, bn = blockIdx.x * 128;
  const int wr = (wave >> 1) * 64, wc = (wave & 1) * 64;

  const int g0 = tid, g1 = tid + 256;
  const u16* Ag0 = A + (size_t)(bm + (g0 >> 2)) * K + (g0 & 3) * 8;
  const u16* Ag1 = A + (size_t)(bm + (g1 >> 2)) * K + (g1 & 3) * 8;
  const u16* Bg0 = B + (size_t)(bn + (g0 >> 2)) * K + (g0 & 3) * 8;
  const u16* Bg1 = B + (size_t)(bn + (g1 >> 2)) * K + (g1 & 3) * 8;

  f32x4 acc[4][4] = {};
  const int nk = K >> 5;
  for (int kt = 0; kt < nk; ++kt) {
    __syncthreads();
    gload16(Ag0 + kt * 32, sA + g0 * 8);
    gload16(Ag1 + kt * 32, sA + g1 * 8);
    gload16(Bg0 + kt * 32, sB + g0 * 8);
    gload16(Bg1 + kt * 32, sB + g1 * 8);
    __syncthreads();
    bf16x8 af[4], bfr[4];
#pragma unroll
    for (int t = 0; t < 4; ++t) {
      __builtin_memcpy(&af[t],  &sA[(wr + t * 16 + l15) * 32 + quad * 8], 16);
      __builtin_memcpy(&bfr[t], &sB[(wc + t * 16 + l15) * 32 + quad * 8], 16);
    }
#pragma unroll
    for (int i = 0; i < 4; ++i)
#pragma unroll
      for (int j = 0; j < 4; ++j)
        acc[i][j] = MFMA16(af[i], bfr[j], acc[i][j]);
  }

  // epilogue: D[row=(lane>>4)*4+r][col=lane&15]
#pragma unroll
  for (int i = 0; i < 4; ++i) {
    const int row0 = bm + wr + i * 16 + quad * 4;
#pragma unroll
    for (int j = 0; j < 4; ++j) {
      const int col = bn + wc + j * 16 + l15;
      const float bv = bias[col];
      if (MODE == 0) {
#pragma unroll
        for (int r = 0; r < 4; ++r)
          outF[(size_t)(row0 + r) * N + col] = acc[i][j][r] + bv;
      } else {
        const int s = col / DIMC;
        const int rem = col - s * DIMC;
        const int h = rem >> 6, d = rem & 63;
        const int b = row0 >> 10, n0 = row0 & 1023;
        const int bh = b * NHEAD + h;
        if (s == 2) {            // V transposed: [bh][d][n]
          u16 pk[4];
#pragma unroll
          for (int r = 0; r < 4; ++r) pk[r] = f2bf(acc[i][j][r] + bv);
          __builtin_memcpy(Vt + (((size_t)bh * 64 + d) << 10) + n0, pk, 8);
        } else {                 // Q/K: [bh][n][d]; Q pre-scaled by QSCALE
          const float sc = (s == 0) ? QSCALE : 1.0f;
          u16* dst = (s == 0 ? Qb : Kb) + (((size_t)bh << 10) + n0) * 64 + d;
#pragma unroll
          for (int r = 0; r < 4; ++r) dst[r * 64] = f2bf((acc[i][j][r] + bv) * sc);
        }
      }
    }
  }
}

// ---------------- flash attention (no-max streaming softmax, S^T orientation) ----
// grid = B*H*8 = 768 blocks; block = 128 Q rows, 4 waves x 32 rows; 64-key chunks.
// LDS rows are 64 u16 with 16B-chunk XOR swizzle: chunk' = chunk ^ (row & 7).
// Every b128 access then hits each bank exactly 8x (the minimum); b64 is 2-way (free).
__device__ __forceinline__ int sw(int row, int chunk) {
  return row * 64 + ((chunk ^ (row & 7)) << 3);   // u16 offset
}

__global__ __launch_bounds__(256, 3)
void attn_fwd(const u16* __restrict__ Qb, const u16* __restrict__ Kb,
              const u16* __restrict__ Vt, u16* __restrict__ AO) {
  __shared__ __align__(16) u16 sK[64 * 64];        // [key][d], swizzled
  __shared__ __align__(16) u16 sV[64 * 64];        // [d][key], swizzled
  __shared__ __align__(16) u16 sP[4][32 * 64];     // per-wave [q][key], swizzled
  const int tid = threadIdx.x;
  const int wave = tid >> 6, lane = tid & 63;
  const int quad = lane >> 4, l15 = lane & 15;
  const int bid = blockIdx.x;
  const int qb = bid & 7, bh = bid >> 3;           // bh in [0,96)
  const int b = bh / NHEAD, h = bh - b * NHEAD;
  const u16* Qp = Qb + ((size_t)bh << 16);
  const u16* Kp = Kb + ((size_t)bh << 16);
  const u16* Vp = Vt + ((size_t)bh << 16);
  u16* sPw = sP[wave];
  const int qrow0 = qb * 128 + wave * 32;

  // Q fragments in registers (B-operand: lane l15 = q, quad*8+j = d), pre-scaled.
  bf16x8 qf[2][2];
#pragma unroll
  for (int qt = 0; qt < 2; ++qt)
#pragma unroll
    for (int ks = 0; ks < 2; ++ks)
      __builtin_memcpy(&qf[qt][ks],
                       Qp + (qrow0 + qt * 16 + l15) * 64 + ks * 32 + quad * 8, 16);

  f32x4 oacc[4][2] = {};   // O^T accum: [dtile][qtile], row=d, col=q
  float Lsum[2] = {0.f, 0.f};

  for (int kc = 0; kc < 16; ++kc) {
    __syncthreads();
    // stage K chunk (contiguous 8KB) and V chunk (64 rows of 128B)
#pragma unroll
    for (int i = 0; i < 2; ++i) {
      const int g = i * 256 + tid, row = g >> 3, seg = g & 7;
      uint4 vk = *(const uint4*)(Kp + (kc << 12) + g * 8);
      uint4 vv = *(const uint4*)(Vp + (row << 10) + (kc << 6) + seg * 8);
      *(uint4*)&sK[sw(row, seg)] = vk;
      *(uint4*)&sV[sw(row, seg)] = vv;
    }
    __syncthreads();

    // S^T[key 64][q 32] = K * Q^T  (A=K: m=key, B=Q: n=q)
    f32x4 st[4][2] = {};
#pragma unroll
    for (int ks = 0; ks < 2; ++ks) {
      bf16x8 kf[4];
#pragma unroll
      for (int kt = 0; kt < 4; ++kt)
        kf[kt] = *(const bf16x8*)&sK[sw(kt * 16 + l15, ks * 4 + quad)];
#pragma unroll
      for (int kt = 0; kt < 4; ++kt)
#pragma unroll
        for (int qt = 0; qt < 2; ++qt)
          st[kt][qt] = MFMA16(kf[kt], qf[qt][ks], st[kt][qt]);
    }

    // p = exp2(S) (Q carries 0.125*log2e); accumulate L; pack to sP[q][key]
#pragma unroll
    for (int kt = 0; kt < 4; ++kt)
#pragma unroll
      for (int qt = 0; qt < 2; ++qt) {
        float p0 = __builtin_amdgcn_exp2f(st[kt][qt][0]);
        float p1 = __builtin_amdgcn_exp2f(st[kt][qt][1]);
        float p2 = __builtin_amdgcn_exp2f(st[kt][qt][2]);
        float p3 = __builtin_amdgcn_exp2f(st[kt][qt][3]);
        Lsum[qt] += (p0 + p1) + (p2 + p3);
        uint2 w = { pack2(p0, p1), pack2(p2, p3) };
        // key offset kt*16+quad*4 -> chunk kt*2+(quad>>1), sub (quad&1)*4
        *(uint2*)&sPw[sw(qt * 16 + l15, kt * 2 + (quad >> 1)) + (quad & 1) * 4] = w;
      }

    __builtin_amdgcn_s_waitcnt(0);  // drain sP writes before same-wave reads

    // O^T[d 64][q 32] += V^T * P^T  (A=V^T from sV[d][key], B=P^T from sP[q][key])
#pragma unroll
    for (int ks = 0; ks < 2; ++ks) {
      bf16x8 vf[4], pf[2];
#pragma unroll
      for (int dt = 0; dt < 4; ++dt)
        vf[dt] = *(const bf16x8*)&sV[sw(dt * 16 + l15, ks * 4 + quad)];
#pragma unroll
      for (int qt = 0; qt < 2; ++qt)
        pf[qt] = *(const bf16x8*)&sPw[sw(qt * 16 + l15, ks * 4 + quad)];
#pragma unroll
      for (int dt = 0; dt < 4; ++dt)
#pragma unroll
        for (int qt = 0; qt < 2; ++qt)
          oacc[dt][qt] = MFMA16(vf[dt], pf[qt], oacc[dt][qt]);
    }
  }

  // final: cross-quad L reduction (quad lives in lane bits 4,5), normalize, store
  float inv[2];
#pragma unroll
  for (int qt = 0; qt < 2; ++qt) {
    float l = Lsum[qt];
    l += __shfl_xor(l, 16);
    l += __shfl_xor(l, 32);
    inv[qt] = 1.0f / l;
  }
  // O^T C-layout: row=d=dt*16+quad*4+r, col=q=l15. Pack 4 d's -> 8B store.
#pragma unroll
  for (int dt = 0; dt < 4; ++dt)
#pragma unroll
    for (int qt = 0; qt < 2; ++qt) {
      const int n = qrow0 + qt * 16 + l15;
      uint2 w = { pack2(oacc[dt][qt][0] * inv[qt], oacc[dt][qt][1] * inv[qt]),
                  pack2(oacc[dt][qt][2] * inv[qt], oacc[dt][qt][3] * inv[qt]) };
      *(uint2*)(AO + (size_t)((b << 10) + n) * DIMC + h * 64 + dt * 16 + quad * 4) = w;
    }
}

// ---------------- launch ----------------
extern "C" void kernel_launch(void* const* d_in, const int* in_sizes, int n_in,
                              void* d_out, int out_size, void* d_ws, size_t ws_size,
                              hipStream_t stream) {
  const float* x      = (const float*)d_in[0];   // [8,1024,768]
  const float* w_qkv  = (const float*)d_in[1];   // [2304,768]
  const float* b_qkv  = (const float*)d_in[2];   // [2304]
  const float* w_proj = (const float*)d_in[3];   // [768,768]
  const float* b_proj = (const float*)d_in[4];   // [768]
  float* out = (float*)d_out;

  u16* Xb     = (u16*)d_ws;
  u16* Wqkvb  = Xb + NX;
  u16* Wprojb = Wqkvb + NWQ;
  u16* Qb     = Wprojb + NWP;
  u16* Kb     = Qb + NX;
  u16* Vt     = Kb + NX;
  u16* AO     = Vt + NX;

  cvt_all<<<(NX + NWQ + NWP) / 2048, 256, 0, stream>>>(x, w_qkv, w_proj, Xb);

  dim3 g1(QKVN / 128, NTOK / 128);
  gemm_nt<1><<<g1, 256, 0, stream>>>(Xb, Wqkvb, b_qkv, nullptr, Qb, Kb, Vt,
                                     NTOK, QKVN, DIMC);

  attn_fwd<<<BATCH * NHEAD * (SEQ / 128), 256, 0, stream>>>(Qb, Kb, Vt, AO);

  dim3 g2(DIMC / 128, NTOK / 128);
  gemm_nt<0><<<g2, 256, 0, stream>>>(AO, Wprojb, b_proj, out, nullptr, nullptr, nullptr,
                                     NTOK, DIMC, DIMC);
}